// Round 6
// baseline (602.785 us; speedup 1.0000x reference)
//
#include <hip/hip_runtime.h>
#include <hip/hip_bf16.h>
#include <stdint.h>

#define O_N 100000
#define T_N 400000
#define NCHG1 12500 // 400000/32 for gemm1
#define NCH1 1563   // ceil(400000/256) for gemm2
#define NCH3 391    // ceil(100000/256)

typedef __attribute__((ext_vector_type(8))) short short8;
typedef __attribute__((ext_vector_type(4))) unsigned short us4;
typedef __attribute__((ext_vector_type(4))) float f32x4;
typedef __attribute__((ext_vector_type(16))) float f32x16;
typedef unsigned short ushort_t;

__device__ __forceinline__ unsigned short f2bf(float x) {
    union { float f; unsigned u; } v; v.f = x;
    unsigned u = v.u;
    unsigned rounded = u + 0x7FFF + ((u >> 16) & 1);
    return (unsigned short)(rounded >> 16);
}

__device__ __forceinline__ short8 pack8(f32x4 a, f32x4 b) {
    short8 t;
    t[0] = (short)f2bf(a[0]); t[1] = (short)f2bf(a[1]);
    t[2] = (short)f2bf(a[2]); t[3] = (short)f2bf(a[3]);
    t[4] = (short)f2bf(b[0]); t[5] = (short)f2bf(b[1]);
    t[6] = (short)f2bf(b[2]); t[7] = (short)f2bf(b[3]);
    return t;
}

__device__ __forceinline__ us4 pack4(f32x4 a) {
    us4 t;
    t[0] = f2bf(a[0]); t[1] = f2bf(a[1]); t[2] = f2bf(a[2]); t[3] = f2bf(a[3]);
    return t;
}

// ---------------- 32x32x16 path ----------------
// B-fragment pack for mfma_f32_32x32x16_bf16:
// out[((ks*NT+nt)*64+lane)*8+j] = bf16(W[ks*16 + (lane>>5)*8 + j][col0 + nt*32 + (lane&31)])
__global__ void pack_b32(const float* __restrict__ W, ushort_t* __restrict__ out,
                         int Ksteps, int NT, int ldw, int col0) {
    int idx = blockIdx.x * 256 + threadIdx.x;
    int total = Ksteps * NT * 512;
    if (idx >= total) return;
    int j = idx & 7;
    int lane = (idx >> 3) & 63;
    int t2 = idx >> 9;
    int nt = t2 % NT;
    int ks = t2 / NT;
    int k = ks * 16 + ((lane >> 5) << 3) + j;
    int n = col0 + (nt << 5) + (lane & 31);
    out[idx] = f2bf(W[(size_t)k * ldw + n]);
}

// K1 v4: chunk=32 triples, 4 waves (wave np = 32-col tile), B(W1a) resident in
// REGISTERS (24 x short8), Ast XOR-swizzled double buffer (1 barrier/chunk),
// per-wave LDS h-transpose -> coalesced 2KB hbuf stores (fragment-packed for gemm2).
__global__ __launch_bounds__(256, 2) void gemm1_k(
    const float* __restrict__ obj_vecs, const float* __restrict__ pred_vecs,
    const int* __restrict__ edges,
    const ushort_t* __restrict__ W1a_p, const float* __restrict__ b1a,
    ushort_t* __restrict__ hbuf, float* __restrict__ counts)
{
    __shared__ __align__(16) ushort_t Ast[2][12288]; // 2 x 24 KB, swizzled frag layout
    __shared__ __align__(16) ushort_t hx[4][1280];   // 4 x 2560 B (32 rows x 80 B)
    const int tid = threadIdx.x;
    const int l = tid & 63;
    const int np = tid >> 6;    // wave -> col tile 0..3
    const int hi = l >> 5;
    const int r32 = l & 31;

    // W1a B-fragments resident in registers (96 VGPR)
    short8 Bf[24];
    #pragma unroll
    for (int ks = 0; ks < 24; ++ks)
        Bf[ks] = *reinterpret_cast<const short8*>(&W1a_p[((ks * 4 + np) * 64 + l) * 8]);

    const float bias = b1a[(np << 5) + r32];
    const int2* e2 = (const int2*)edges;

    int c = blockIdx.x;
    f32x4 v[12];
    // prologue: coalesced gather of chunk c (96 consecutive lanes cover one row)
    #pragma unroll
    for (int i = 0; i < 12; ++i) {
        int s = i * 256 + tid;
        int row = s / 96;
        int cc = (s - row * 96) * 4;
        int2 e = e2[c * 32 + row];
        const float* bp = (cc < 128) ? obj_vecs  + (size_t)e.x * 128 + cc
                        : (cc < 256) ? pred_vecs + (size_t)(c * 32 + row) * 128 + (cc - 128)
                                     : obj_vecs  + (size_t)e.y * 128 + (cc - 256);
        v[i] = *reinterpret_cast<const f32x4*>(bp);
    }

    int p = 0;
    for (;;) {
        // stage v -> Ast[p], XOR-swizzled (write side)
        char* astp = (char*)&Ast[p][0];
        #pragma unroll
        for (int i = 0; i < 12; ++i) {
            int s = i * 256 + tid;
            int row = s / 96;
            int cc = (s - row * 96) * 4;
            int W = ((cc >> 3) << 9) + (row << 4) + ((cc & 7) << 1);
            W ^= ((W >> 9) & 31) << 4;
            *reinterpret_cast<us4*>(astp + W) = pack4(v[i]);
        }
        if (tid < 32) {
            int2 e = e2[c * 32 + tid];
            atomicAdd(&counts[e.x], 1.0f);
            atomicAdd(&counts[e.y], 1.0f);
        }
        int cn = c + (int)gridDim.x;
        if (cn < NCHG1) {
            #pragma unroll
            for (int i = 0; i < 12; ++i) {
                int s = i * 256 + tid;
                int row = s / 96;
                int cc = (s - row * 96) * 4;
                int2 e = e2[cn * 32 + row];
                const float* bp = (cc < 128) ? obj_vecs  + (size_t)e.x * 128 + cc
                                : (cc < 256) ? pred_vecs + (size_t)(cn * 32 + row) * 128 + (cc - 128)
                                             : obj_vecs  + (size_t)e.y * 128 + (cc - 256);
                v[i] = *reinterpret_cast<const f32x4*>(bp);
            }
        }
        __syncthreads();

        // compute: 24 MFMA, A from Ast (swizzled read), B from registers
        f32x16 acc = {};
        #pragma unroll
        for (int ks = 0; ks < 24; ++ks) {
            int W = ((ks * 2 + hi) << 9) + (r32 << 4);
            W ^= ((W >> 9) & 31) << 4;
            short8 a = *reinterpret_cast<const short8*>(astp + W);
            acc = __builtin_amdgcn_mfma_f32_32x32x16_bf16(a, Bf[ks], acc, 0, 0, 0);
        }

        // epilogue: acc -> per-wave hx (stride-80 rows, conflict-free) -> hbuf 2KB coalesced
        {
            char* hw = (char*)&hx[np][0];
            int sb = ((((l >> 4) & 1) * 2 + ((l >> 3) & 1)) << 4) + ((l & 7) << 1);
            #pragma unroll
            for (int r = 0; r < 16; ++r) {
                int rl = (r & 3) + ((r >> 2) << 3) + (hi << 2);
                float hv = fmaxf(acc[r] + bias, 0.0f);
                *(ushort_t*)(hw + rl * 80 + sb) = f2bf(hv);
            }
            asm volatile("s_waitcnt lgkmcnt(0)" ::: "memory");
            int base = (l & 15) * 160 + (l >> 4) * 16;
            short8 h0 = *reinterpret_cast<const short8*>(hw + base);
            short8 h1 = *reinterpret_cast<const short8*>(hw + base + 80);
            size_t dst = (size_t)c * 4096 + np * 1024 + l * 16;
            *reinterpret_cast<short8*>(&hbuf[dst])     = h0;
            *reinterpret_cast<short8*>(&hbuf[dst + 8]) = h1;
        }
        if (cn >= NCHG1) break;
        c = cn; p ^= 1;
    }
}

// K2: h(packed) @ W1b + b1b -> 3 nt-groups: {new_s pk-atomic, new_p store, new_o pk-atomic}.
// W1b resident in LDS; pooled accumulated as bf16 via global_atomic_pk_add_bf16.
__global__ __launch_bounds__(512, 2) void gemm2_k(
    const ushort_t* __restrict__ hbuf, const int* __restrict__ edges,
    const ushort_t* __restrict__ W1b_p, const float* __restrict__ b1b,
    ushort_t* __restrict__ pooled_bf, float* __restrict__ new_p)
{
    __shared__ __align__(16) ushort_t Wl[49152]; // 96 KB
    const int tid = threadIdx.x;
    const int l = tid & 63;
    const int w = tid >> 6;
    const int q = l >> 5;
    const int r32 = l & 31;

    {
        const short8* s = reinterpret_cast<const short8*>(W1b_p);
        short8* d = reinterpret_cast<short8*>(Wl);
        #pragma unroll
        for (int i = 0; i < 12; ++i) d[i * 512 + tid] = s[i * 512 + tid];
    }
    __syncthreads();

    float bias[12];
    #pragma unroll
    for (int nt = 0; nt < 12; ++nt) bias[nt] = b1b[(nt << 5) + r32];

    for (int c = blockIdx.x; c < NCH1; c += gridDim.x) {
        int t32g = c * 8 + w;
        if (t32g > T_N / 32 - 1) t32g = T_N / 32 - 1;

        short8 af[8];
        #pragma unroll
        for (int ks = 0; ks < 8; ++ks)
            af[ks] = *reinterpret_cast<const short8*>(
                &hbuf[(size_t)(((t32g * 8 + ks) * 2 + q) * 32 + r32) * 8]);

        #pragma unroll
        for (int g = 0; g < 3; ++g) {
            f32x16 acc[4] = {};
            #pragma unroll
            for (int ks = 0; ks < 8; ++ks) {
                #pragma unroll
                for (int nt2 = 0; nt2 < 4; ++nt2) {
                    short8 bf = *reinterpret_cast<const short8*>(&Wl[((ks * 12 + (g << 2) + nt2) * 64 + l) * 8]);
                    acc[nt2] = __builtin_amdgcn_mfma_f32_32x32x16_bf16(af[ks], bf, acc[nt2], 0, 0, 0);
                }
            }
            if (g == 1) {
                #pragma unroll
                for (int nt2 = 0; nt2 < 4; ++nt2) {
                    #pragma unroll
                    for (int r = 0; r < 16; ++r) {
                        int rl = (r & 3) + ((r >> 2) << 3) + (q << 2);
                        int trow2 = c * 256 + w * 32 + rl;
                        if (trow2 < T_N)
                            new_p[(size_t)trow2 * 128 + (nt2 << 5) + r32] = acc[nt2][r] + bias[4 + nt2];
                    }
                }
            } else {
                #pragma unroll
                for (int r = 0; r < 16; ++r) {
                    int rl = (r & 3) + ((r >> 2) << 3) + (q << 2);
                    int trow2 = c * 256 + w * 32 + rl;
                    bool v2 = trow2 < T_N;
                    int t2 = v2 ? trow2 : T_N - 1;
                    int2 e2 = ((const int2*)edges)[t2];
                    int seg = (g == 0) ? e2.x : e2.y;
                    ushort_t* pb = pooled_bf + (size_t)seg * 128;
                    #pragma unroll
                    for (int nt2 = 0; nt2 < 4; ++nt2) {
                        float val = acc[nt2][r] + bias[(g << 2) + nt2];
                        float other = __shfl_xor(val, 1, 64);
                        if (v2 && !(r32 & 1)) {
                            unsigned dat = (unsigned)f2bf(val) | ((unsigned)f2bf(other) << 16);
                            uint64_t addr = (uint64_t)(uintptr_t)(pb + (nt2 << 5) + r32);
                            asm volatile("global_atomic_pk_add_bf16 %0, %1, off"
                                         :: "v"(addr), "v"(dat) : "memory");
                        }
                    }
                }
            }
        }
    }
}

// K3: pooled_bf/counts -> relu(x@W2a+b2a)@W2b+b2b -> new_obj (f32, d_out).
__global__ __launch_bounds__(512, 2) void objects_k32(
    const ushort_t* __restrict__ pooled_bf, const float* __restrict__ counts,
    const ushort_t* __restrict__ W2a_p, const float* __restrict__ b2a,
    const ushort_t* __restrict__ W2b_p, const float* __restrict__ b2b,
    float* __restrict__ outp)
{
    __shared__ __align__(16) ushort_t Wa[16384];   // 32 KB
    __shared__ __align__(16) ushort_t Wb[16384];   // 32 KB
    __shared__ __align__(16) ushort_t hx[8][4096]; // 64 KB, per-wave swizzled exchange
    const int tid = threadIdx.x;
    const int l = tid & 63;
    const int w = tid >> 6;
    const int q = l >> 5;
    const int r32 = l & 31;

    {
        const short8* sa = reinterpret_cast<const short8*>(W2a_p);
        const short8* sb = reinterpret_cast<const short8*>(W2b_p);
        short8* da = reinterpret_cast<short8*>(Wa);
        short8* db = reinterpret_cast<short8*>(Wb);
        #pragma unroll
        for (int i = 0; i < 4; ++i) { da[i * 512 + tid] = sa[i * 512 + tid]; db[i * 512 + tid] = sb[i * 512 + tid]; }
    }
    __syncthreads();

    float ba[4], bb[4];
    #pragma unroll
    for (int nt = 0; nt < 4; ++nt) { ba[nt] = b2a[(nt << 5) + r32]; bb[nt] = b2b[(nt << 5) + r32]; }

    for (int c = blockIdx.x; c < NCH3; c += gridDim.x) {
        int row = c * 256 + w * 32 + r32;
        int rr = row < O_N ? row : O_N - 1;
        float inv = 1.0f / fmaxf(counts[rr], 1.0f);

        short8 af[8];
        #pragma unroll
        for (int ks = 0; ks < 8; ++ks) {
            short8 raw = *reinterpret_cast<const short8*>(&pooled_bf[(size_t)rr * 128 + (ks << 4) + (q << 3)]);
            short8 a;
            #pragma unroll
            for (int j = 0; j < 8; ++j) {
                union { float f; unsigned u; } t;
                t.u = ((unsigned)(unsigned short)raw[j]) << 16;
                a[j] = (short)f2bf(t.f * inv);
            }
            af[ks] = a;
        }

        f32x16 acc[4] = {};
        #pragma unroll
        for (int ks = 0; ks < 8; ++ks) {
            #pragma unroll
            for (int nt = 0; nt < 4; ++nt) {
                short8 bf = *reinterpret_cast<const short8*>(&Wa[(((ks << 2) + nt) * 64 + l) * 8]);
                acc[nt] = __builtin_amdgcn_mfma_f32_32x32x16_bf16(af[ks], bf, acc[nt], 0, 0, 0);
            }
        }

        char* hxw = (char*)&hx[w][0];
        #pragma unroll
        for (int nt = 0; nt < 4; ++nt) {
            #pragma unroll
            for (int r = 0; r < 16; ++r) {
                int rl = (r & 3) + ((r >> 2) << 3) + (q << 2);
                float hv = fmaxf(acc[nt][r] + ba[nt], 0.0f);
                int off = rl * 256 + (((nt << 5) + r32) << 1);
                off ^= (rl & 15) << 4;
                *(ushort_t*)(hxw + off) = f2bf(hv);
            }
        }
        __syncthreads();

        short8 af2[8];
        #pragma unroll
        for (int ks = 0; ks < 8; ++ks) {
            int off = r32 * 256 + (ks << 5) + (q << 4);
            off ^= (r32 & 15) << 4;
            af2[ks] = *reinterpret_cast<const short8*>(hxw + off);
        }

        f32x16 acc2[4] = {};
        #pragma unroll
        for (int ks = 0; ks < 8; ++ks) {
            #pragma unroll
            for (int nt = 0; nt < 4; ++nt) {
                short8 bf = *reinterpret_cast<const short8*>(&Wb[(((ks << 2) + nt) * 64 + l) * 8]);
                acc2[nt] = __builtin_amdgcn_mfma_f32_32x32x16_bf16(af2[ks], bf, acc2[nt], 0, 0, 0);
            }
        }

        #pragma unroll
        for (int nt = 0; nt < 4; ++nt) {
            #pragma unroll
            for (int r = 0; r < 16; ++r) {
                int rl = (r & 3) + ((r >> 2) << 3) + (q << 2);
                int row2 = c * 256 + w * 32 + rl;
                if (row2 < O_N) outp[(size_t)row2 * 128 + (nt << 5) + r32] = acc2[nt][r] + bb[nt];
            }
        }
        __syncthreads();
    }
}

// ---------------- fallback path (round-1, 16x16x32, known-good) ----------------
__global__ void pack_b(const float* __restrict__ W, unsigned short* __restrict__ out,
                       int K, int Ntiles, int ldw, int col0) {
    int idx = blockIdx.x * 256 + threadIdx.x;
    int total = K * Ntiles * 16;
    if (idx >= total) return;
    int j = idx & 7;
    int lane = (idx >> 3) & 63;
    int t2 = idx >> 9;
    int ntile = t2 % Ntiles;
    int kstep = t2 / Ntiles;
    int k = kstep * 32 + ((lane >> 4) << 3) + j;
    int n = (ntile << 4) + (lane & 15);
    out[idx] = f2bf(W[(size_t)k * ldw + col0 + n]);
}

__device__ __forceinline__ void stage_w(const unsigned short* __restrict__ src,
                                        unsigned short* __restrict__ dst, int tid) {
    const short8* s = reinterpret_cast<const short8*>(src);
    short8* d = reinterpret_cast<short8*>(dst);
    d[tid] = s[tid];
    d[tid + 256] = s[tid + 256];
}

__global__ __launch_bounds__(256, 2) void triples_kernel(
    const float* __restrict__ obj_vecs, const float* __restrict__ pred_vecs,
    const int* __restrict__ edges,
    const unsigned short* __restrict__ W1a_p, const float* __restrict__ b1a,
    const unsigned short* __restrict__ W1b_p, const float* __restrict__ b1b,
    float* __restrict__ pooled, float* __restrict__ new_p, float* __restrict__ counts)
{
    __shared__ __align__(16) unsigned short Apack[24576];
    __shared__ __align__(16) unsigned short Wbuf[2][4096];
    __shared__ int sseg[64], oseg[64];
    const int tid = threadIdx.x;
    const int lane = tid & 63;
    const int w = tid >> 6;
    const int t0 = blockIdx.x * 64;
    if (tid < 64) {
        int s = edges[2 * (t0 + tid)];
        int o = edges[2 * (t0 + tid) + 1];
        sseg[tid] = s; oseg[tid] = o;
        atomicAdd(&counts[s], 1.0f);
        atomicAdd(&counts[o], 1.0f);
    }
    __syncthreads();
    for (int it = 0; it < 24; ++it) {
        int idx = it * 256 + tid;
        int r = idx / 96;
        int c = (idx % 96) * 4;
        const float* srcp;
        if (c < 128)      srcp = obj_vecs  + (size_t)sseg[r] * 128 + c;
        else if (c < 256) srcp = pred_vecs + (size_t)(t0 + r) * 128 + (c - 128);
        else              srcp = obj_vecs  + (size_t)oseg[r] * 128 + (c - 256);
        f32x4 v = *reinterpret_cast<const f32x4*>(srcp);
        int off = (((r >> 4) * 12 + (c >> 5)) << 9)
                + (((r & 15) | (((c & 31) >> 3) << 4)) << 3) + (c & 7);
        Apack[off + 0] = f2bf(v[0]); Apack[off + 1] = f2bf(v[1]);
        Apack[off + 2] = f2bf(v[2]); Apack[off + 3] = f2bf(v[3]);
    }
    stage_w(W1a_p, Wbuf[0], tid);
    __syncthreads();
    f32x4 acc[8];
    #pragma unroll
    for (int n = 0; n < 8; ++n) acc[n] = (f32x4){0.f, 0.f, 0.f, 0.f};
    for (int kk = 0; kk < 12; ++kk) {
        if (kk < 11) stage_w(W1a_p + (kk + 1) * 4096, Wbuf[(kk + 1) & 1], tid);
        short8 a = *reinterpret_cast<const short8*>(&Apack[((w * 12 + kk) << 9) + (lane << 3)]);
        const unsigned short* wb = Wbuf[kk & 1];
        #pragma unroll
        for (int n = 0; n < 8; ++n) {
            short8 b = *reinterpret_cast<const short8*>(&wb[((n << 6) + lane) << 3]);
            acc[n] = __builtin_amdgcn_mfma_f32_16x16x32_bf16(a, b, acc[n], 0, 0, 0);
        }
        __syncthreads();
    }
    #pragma unroll
    for (int n = 0; n < 8; ++n) {
        int col = (n << 4) + (lane & 15);
        float bias = b1a[col];
        int base = ((w * 4 + (col >> 5)) << 9) + (col & 7);
        int chi = ((col & 31) >> 3) << 4;
        #pragma unroll
        for (int jj = 0; jj < 4; ++jj) {
            int rloc = ((lane >> 4) << 2) + jj;
            float hv = acc[n][jj] + bias;
            hv = hv > 0.f ? hv : 0.f;
            Apack[base + ((rloc | chi) << 3)] = f2bf(hv);
        }
    }
    for (int g = 0; g < 3; ++g) {
        const unsigned short* Wsrc = W1b_p + g * 16384;
        stage_w(Wsrc, Wbuf[0], tid);
        __syncthreads();
        f32x4 acc2[8];
        #pragma unroll
        for (int n = 0; n < 8; ++n) acc2[n] = (f32x4){0.f, 0.f, 0.f, 0.f};
        for (int kk = 0; kk < 4; ++kk) {
            if (kk < 3) stage_w(Wsrc + (kk + 1) * 4096, Wbuf[(kk + 1) & 1], tid);
            short8 a = *reinterpret_cast<const short8*>(&Apack[((w * 4 + kk) << 9) + (lane << 3)]);
            const unsigned short* wb = Wbuf[kk & 1];
            #pragma unroll
            for (int n = 0; n < 8; ++n) {
                short8 b = *reinterpret_cast<const short8*>(&wb[((n << 6) + lane) << 3]);
                acc2[n] = __builtin_amdgcn_mfma_f32_16x16x32_bf16(a, b, acc2[n], 0, 0, 0);
            }
            __syncthreads();
        }
        #pragma unroll
        for (int n = 0; n < 8; ++n) {
            int col = (n << 4) + (lane & 15);
            float bias = b1b[g * 128 + col];
            #pragma unroll
            for (int jj = 0; jj < 4; ++jj) {
                int rloc = (w << 4) + ((lane >> 4) << 2) + jj;
                float val = acc2[n][jj] + bias;
                if (g == 1) {
                    new_p[(size_t)(t0 + rloc) * 128 + col] = val;
                } else {
                    int seg = (g == 0) ? sseg[rloc] : oseg[rloc];
                    atomicAdd(&pooled[(size_t)seg * 128 + col], val);
                }
            }
        }
    }
}

__global__ __launch_bounds__(256, 2) void objects_kernel(
    const float* __restrict__ counts,
    const unsigned short* __restrict__ W2a_p, const float* __restrict__ b2a,
    const unsigned short* __restrict__ W2b_p, const float* __restrict__ b2b,
    float* __restrict__ inout)
{
    __shared__ __align__(16) unsigned short Apack[8192];
    __shared__ __align__(16) unsigned short Hpack[8192];
    __shared__ __align__(16) unsigned short Wbuf[2][4096];
    const int tid = threadIdx.x;
    const int lane = tid & 63;
    const int w = tid >> 6;
    const int r0 = blockIdx.x * 64;
    for (int it = 0; it < 8; ++it) {
        int idx = it * 256 + tid;
        int r = idx >> 5;
        int c = (idx & 31) << 2;
        int row = r0 + r;
        float vals[4] = {0.f, 0.f, 0.f, 0.f};
        if (row < O_N) {
            f32x4 v = *reinterpret_cast<const f32x4*>(&inout[(size_t)row * 128 + c]);
            float inv = 1.0f / fmaxf(counts[row], 1.0f);
            vals[0] = v[0] * inv; vals[1] = v[1] * inv;
            vals[2] = v[2] * inv; vals[3] = v[3] * inv;
        }
        int off = (((r >> 4) * 4 + (c >> 5)) << 9)
                + (((r & 15) | (((c & 31) >> 3) << 4)) << 3) + (c & 7);
        Apack[off + 0] = f2bf(vals[0]); Apack[off + 1] = f2bf(vals[1]);
        Apack[off + 2] = f2bf(vals[2]); Apack[off + 3] = f2bf(vals[3]);
    }
    stage_w(W2a_p, Wbuf[0], tid);
    __syncthreads();
    f32x4 acc[8];
    #pragma unroll
    for (int n = 0; n < 8; ++n) acc[n] = (f32x4){0.f, 0.f, 0.f, 0.f};
    for (int kk = 0; kk < 4; ++kk) {
        if (kk < 3) stage_w(W2a_p + (kk + 1) * 4096, Wbuf[(kk + 1) & 1], tid);
        short8 a = *reinterpret_cast<const short8*>(&Apack[((w * 4 + kk) << 9) + (lane << 3)]);
        const unsigned short* wb = Wbuf[kk & 1];
        #pragma unroll
        for (int n = 0; n < 8; ++n) {
            short8 b = *reinterpret_cast<const short8*>(&wb[((n << 6) + lane) << 3]);
            acc[n] = __builtin_amdgcn_mfma_f32_16x16x32_bf16(a, b, acc[n], 0, 0, 0);
        }
        __syncthreads();
    }
    #pragma unroll
    for (int n = 0; n < 8; ++n) {
        int col = (n << 4) + (lane & 15);
        float bias = b2a[col];
        int base = ((w * 4 + (col >> 5)) << 9) + (col & 7);
        int chi = ((col & 31) >> 3) << 4;
        #pragma unroll
        for (int jj = 0; jj < 4; ++jj) {
            int rloc = ((lane >> 4) << 2) + jj;
            float hv = acc[n][jj] + bias;
            hv = hv > 0.f ? hv : 0.f;
            Hpack[base + ((rloc | chi) << 3)] = f2bf(hv);
        }
    }
    stage_w(W2b_p, Wbuf[0], tid);
    __syncthreads();
    f32x4 acc2[8];
    #pragma unroll
    for (int n = 0; n < 8; ++n) acc2[n] = (f32x4){0.f, 0.f, 0.f, 0.f};
    for (int kk = 0; kk < 4; ++kk) {
        if (kk < 3) stage_w(W2b_p + (kk + 1) * 4096, Wbuf[(kk + 1) & 1], tid);
        short8 a = *reinterpret_cast<const short8*>(&Hpack[((w * 4 + kk) << 9) + (lane << 3)]);
        const unsigned short* wb = Wbuf[kk & 1];
        #pragma unroll
        for (int n = 0; n < 8; ++n) {
            short8 b = *reinterpret_cast<const short8*>(&wb[((n << 6) + lane) << 3]);
            acc2[n] = __builtin_amdgcn_mfma_f32_16x16x32_bf16(a, b, acc2[n], 0, 0, 0);
        }
        __syncthreads();
    }
    #pragma unroll
    for (int n = 0; n < 8; ++n) {
        int col = (n << 4) + (lane & 15);
        float bias = b2b[col];
        #pragma unroll
        for (int jj = 0; jj < 4; ++jj) {
            int rloc = (w << 4) + ((lane >> 4) << 2) + jj;
            int row = r0 + rloc;
            if (row < O_N) inout[(size_t)row * 128 + col] = acc2[n][jj] + bias;
        }
    }
}

extern "C" void kernel_launch(void* const* d_in, const int* in_sizes, int n_in,
                              void* d_out, int out_size, void* d_ws, size_t ws_size,
                              hipStream_t stream)
{
    const float* obj   = (const float*)d_in[0];
    const float* pred  = (const float*)d_in[1];
    const int*   edges = (const int*)d_in[2];
    const float* W1a = (const float*)d_in[3];
    const float* b1a = (const float*)d_in[4];
    const float* W1b = (const float*)d_in[5];
    const float* b1b = (const float*)d_in[6];
    const float* W2a = (const float*)d_in[7];
    const float* b2a = (const float*)d_in[8];
    const float* W2b = (const float*)d_in[9];
    const float* b2b = (const float*)d_in[10];

    float* out    = (float*)d_out;
    float* new_p  = out + (size_t)O_N * 128;   // T x 128

    uintptr_t wsbase = (uintptr_t)d_ws;
    float* counts = (float*)wsbase;
    uintptr_t p = (wsbase + (size_t)O_N * 4 + 255) & ~(uintptr_t)255;
    ushort_t* pooled_bf = (ushort_t*)p;  p += (size_t)O_N * 128 * 2;   // 25.6 MB
    ushort_t* W1a_p = (ushort_t*)p;  p += (size_t)49152 * 2;
    ushort_t* W1b_p = (ushort_t*)p;  p += (size_t)49152 * 2;
    ushort_t* W2a_p = (ushort_t*)p;  p += (size_t)16384 * 2;
    ushort_t* W2b_p = (ushort_t*)p;  p += (size_t)16384 * 2;
    ushort_t* hbuf  = (ushort_t*)p;  p += (size_t)T_N * 128 * 2;       // 102.4 MB (fragment-packed)
    size_t need = p - wsbase;

    hipMemsetAsync(counts, 0, (size_t)O_N * sizeof(float), stream);

    if (ws_size >= need) {
        hipMemsetAsync(pooled_bf, 0, (size_t)O_N * 128 * 2, stream);

        pack_b32<<<192, 256, 0, stream>>>(W1a, W1a_p, 24, 4, 128, 0);   // 49152 items
        pack_b32<<<192, 256, 0, stream>>>(W1b, W1b_p, 8, 12, 384, 0);   // 49152 items
        pack_b32<<<64, 256, 0, stream>>>(W2a, W2a_p, 8, 4, 128, 0);     // 16384 items
        pack_b32<<<64, 256, 0, stream>>>(W2b, W2b_p, 8, 4, 128, 0);     // 16384 items

        gemm1_k<<<512, 256, 0, stream>>>(obj, pred, edges, W1a_p, b1a, hbuf, counts);
        gemm2_k<<<256, 512, 0, stream>>>(hbuf, edges, W1b_p, b1b, pooled_bf, new_p);
        objects_k32<<<391, 512, 0, stream>>>(pooled_bf, counts, W2a_p, b2a, W2b_p, b2b, out);
    } else {
        // fallback: round-1 fused path (correct, slower); pooled f32 in d_out
        float* pooled = out;
        hipMemsetAsync(pooled, 0, (size_t)O_N * 128 * sizeof(float), stream);

        pack_b<<<192, 256, 0, stream>>>(W1a, W1a_p, 384, 8, 128, 0);
        pack_b<<<64, 256, 0, stream>>>(W1b, W1b_p,         128, 8, 384, 0);
        pack_b<<<64, 256, 0, stream>>>(W1b, W1b_p + 16384, 128, 8, 384, 128);
        pack_b<<<64, 256, 0, stream>>>(W1b, W1b_p + 32768, 128, 8, 384, 256);
        pack_b<<<64, 256, 0, stream>>>(W2a, W2a_p, 128, 8, 128, 0);
        pack_b<<<64, 256, 0, stream>>>(W2b, W2b_p, 128, 8, 128, 0);

        triples_kernel<<<T_N / 64, 256, 0, stream>>>(obj, pred, edges,
                                                     W1a_p, b1a, W1b_p, b1b,
                                                     pooled, new_p, counts);
        objects_kernel<<<(O_N + 63) / 64, 256, 0, stream>>>(counts, W2a_p, b2a, W2b_p, b2b, out);
    }
}

// Round 7
// 460.950 us; speedup vs baseline: 1.3077x; 1.3077x over previous
//
#include <hip/hip_runtime.h>
#include <hip/hip_bf16.h>
#include <stdint.h>

#define O_N 100000
#define T_N 400000
#define NCH1 1563   // ceil(400000/256) for gemm2
#define NCH3 391    // ceil(100000/256)
#define NCHW 25000  // 400000/16 wave-chunks for gemm1

typedef __attribute__((ext_vector_type(8))) short short8;
typedef __attribute__((ext_vector_type(4))) unsigned short us4;
typedef __attribute__((ext_vector_type(4))) float f32x4;
typedef __attribute__((ext_vector_type(16))) float f32x16;
typedef unsigned short ushort_t;

__device__ __forceinline__ unsigned short f2bf(float x) {
    union { float f; unsigned u; } v; v.f = x;
    unsigned u = v.u;
    unsigned rounded = u + 0x7FFF + ((u >> 16) & 1);
    return (unsigned short)(rounded >> 16);
}

__device__ __forceinline__ short8 pack8(f32x4 a, f32x4 b) {
    short8 t;
    t[0] = (short)f2bf(a[0]); t[1] = (short)f2bf(a[1]);
    t[2] = (short)f2bf(a[2]); t[3] = (short)f2bf(a[3]);
    t[4] = (short)f2bf(b[0]); t[5] = (short)f2bf(b[1]);
    t[6] = (short)f2bf(b[2]); t[7] = (short)f2bf(b[3]);
    return t;
}

// B-fragment pack for mfma_f32_32x32x16_bf16 (used by gemm2/objects)
__global__ void pack_b32(const float* __restrict__ W, ushort_t* __restrict__ out,
                         int Ksteps, int NT, int ldw, int col0) {
    int idx = blockIdx.x * 256 + threadIdx.x;
    int total = Ksteps * NT * 512;
    if (idx >= total) return;
    int j = idx & 7;
    int lane = (idx >> 3) & 63;
    int t2 = idx >> 9;
    int nt = t2 % NT;
    int ks = t2 / NT;
    int k = ks * 16 + ((lane >> 5) << 3) + j;
    int n = col0 + (nt << 5) + (lane & 31);
    out[idx] = f2bf(W[(size_t)k * ldw + n]);
}

// B-fragment pack for mfma_f32_16x16x32_bf16 (used by gemm1 v5 and fallback)
__global__ void pack_b(const float* __restrict__ W, unsigned short* __restrict__ out,
                       int K, int Ntiles, int ldw, int col0) {
    int idx = blockIdx.x * 256 + threadIdx.x;
    int total = K * Ntiles * 16;
    if (idx >= total) return;
    int j = idx & 7;
    int lane = (idx >> 3) & 63;
    int t2 = idx >> 9;
    int ntile = t2 % Ntiles;
    int kstep = t2 / Ntiles;
    int k = kstep * 32 + ((lane >> 4) << 3) + j;
    int n = (ntile << 4) + (lane & 15);
    out[idx] = f2bf(W[(size_t)k * ldw + col0 + n]);
}

// standalone segment-count kernel (removed from gemm1's hot loop)
__global__ void counts_k(const int* __restrict__ edges, float* __restrict__ counts) {
    int idx = blockIdx.x * 256 + threadIdx.x;
    if (idx >= T_N) return;
    int2 e = ((const int2*)edges)[idx];
    atomicAdd(&counts[e.x], 1.0f);
    atomicAdd(&counts[e.y], 1.0f);
}

// K1 v5: 16 waves/block, 1 block/CU, ZERO steady-state barriers. Each wave owns
// 16 triples/iter: per-lane direct gather -> 16x16x32 A-frags (3 K-groups, low VGPR),
// W1a resident in LDS (16x16 B-frag layout), per-wave 2-pass LDS transpose ->
// coalesced row-major hbuf stores.
__global__ __launch_bounds__(1024, 4) void gemm1_k(
    const float* __restrict__ obj_vecs, const float* __restrict__ pred_vecs,
    const int* __restrict__ edges,
    const ushort_t* __restrict__ W1a_p, const float* __restrict__ b1a,
    ushort_t* __restrict__ hbuf)
{
    __shared__ __align__(16) ushort_t Wl[49152];    // 96 KB
    __shared__ __align__(16) ushort_t hx[16][1088]; // 16 waves x (16 rows x 68 ushorts)
    const int tid = threadIdx.x;
    const int l = tid & 63;
    const int w = tid >> 6;       // 0..15
    const int r16 = l & 15;
    const int kq = l >> 4;        // 0..3

    {
        const short8* s = reinterpret_cast<const short8*>(W1a_p);
        short8* d = reinterpret_cast<short8*>(Wl);
        #pragma unroll
        for (int i = 0; i < 6; ++i) d[i * 1024 + tid] = s[i * 1024 + tid];
    }
    __syncthreads();

    float bias[8];
    #pragma unroll
    for (int nt = 0; nt < 8; ++nt) bias[nt] = b1a[nt * 16 + r16];

    ushort_t* hw = hx[w];
    const int2* e2 = (const int2*)edges;
    const int stride = gridDim.x * 16;

    for (int ch = blockIdx.x * 16 + w; ch < NCHW; ch += stride) {
        int tri = ch * 16 + r16;
        int2 e = e2[tri];
        const float* ps = obj_vecs  + (size_t)e.x * 128;
        const float* pp = pred_vecs + (size_t)tri * 128;
        const float* po = obj_vecs  + (size_t)e.y * 128;

        f32x4 acc[8];
        #pragma unroll
        for (int nt = 0; nt < 8; ++nt) acc[nt] = (f32x4){0.f, 0.f, 0.f, 0.f};

        // ---- K-group 0: obj[s], global ks 0..3 ----
        {
            short8 af[4];
            #pragma unroll
            for (int ks = 0; ks < 4; ++ks) {
                f32x4 v0 = *reinterpret_cast<const f32x4*>(ps + ks * 32 + kq * 8);
                f32x4 v1 = *reinterpret_cast<const f32x4*>(ps + ks * 32 + kq * 8 + 4);
                af[ks] = pack8(v0, v1);
            }
            #pragma unroll
            for (int ks = 0; ks < 4; ++ks)
                #pragma unroll
                for (int nt = 0; nt < 8; ++nt) {
                    short8 b = *reinterpret_cast<const short8*>(&Wl[((ks * 8 + nt) * 64 + l) * 8]);
                    acc[nt] = __builtin_amdgcn_mfma_f32_16x16x32_bf16(af[ks], b, acc[nt], 0, 0, 0);
                }
        }
        // ---- K-group 1: pred, global ks 4..7 ----
        {
            short8 af[4];
            #pragma unroll
            for (int ks = 0; ks < 4; ++ks) {
                f32x4 v0 = *reinterpret_cast<const f32x4*>(pp + ks * 32 + kq * 8);
                f32x4 v1 = *reinterpret_cast<const f32x4*>(pp + ks * 32 + kq * 8 + 4);
                af[ks] = pack8(v0, v1);
            }
            #pragma unroll
            for (int ks = 0; ks < 4; ++ks)
                #pragma unroll
                for (int nt = 0; nt < 8; ++nt) {
                    short8 b = *reinterpret_cast<const short8*>(&Wl[(((ks + 4) * 8 + nt) * 64 + l) * 8]);
                    acc[nt] = __builtin_amdgcn_mfma_f32_16x16x32_bf16(af[ks], b, acc[nt], 0, 0, 0);
                }
        }
        // ---- K-group 2: obj[o], global ks 8..11 ----
        {
            short8 af[4];
            #pragma unroll
            for (int ks = 0; ks < 4; ++ks) {
                f32x4 v0 = *reinterpret_cast<const f32x4*>(po + ks * 32 + kq * 8);
                f32x4 v1 = *reinterpret_cast<const f32x4*>(po + ks * 32 + kq * 8 + 4);
                af[ks] = pack8(v0, v1);
            }
            #pragma unroll
            for (int ks = 0; ks < 4; ++ks)
                #pragma unroll
                for (int nt = 0; nt < 8; ++nt) {
                    short8 b = *reinterpret_cast<const short8*>(&Wl[(((ks + 8) * 8 + nt) * 64 + l) * 8]);
                    acc[nt] = __builtin_amdgcn_mfma_f32_16x16x32_bf16(af[ks], b, acc[nt], 0, 0, 0);
                }
        }

        // ---- epilogue: two half-width passes through per-wave hx, coalesced out ----
        #pragma unroll
        for (int p = 0; p < 2; ++p) {
            #pragma unroll
            for (int nt2 = 0; nt2 < 4; ++nt2) {
                int nt = p * 4 + nt2;
                #pragma unroll
                for (int j = 0; j < 4; ++j) {
                    int row = kq * 4 + j;                     // C/D: col=l&15, row=(l>>4)*4+j
                    float hv = fmaxf(acc[nt][j] + bias[nt], 0.0f);
                    hw[row * 68 + nt2 * 16 + r16] = f2bf(hv);
                }
            }
            asm volatile("s_waitcnt lgkmcnt(0)" ::: "memory");
            #pragma unroll
            for (int it = 0; it < 2; ++it) {
                short8 hv = *reinterpret_cast<const short8*>(&hw[(l >> 2) * 68 + (l & 3) * 16 + it * 8]);
                *reinterpret_cast<short8*>(
                    &hbuf[(size_t)(ch * 16 + (l >> 2)) * 128 + p * 64 + (l & 3) * 16 + it * 8]) = hv;
            }
            asm volatile("s_waitcnt lgkmcnt(0)" ::: "memory");
        }
    }
}

// K2: h(row-major) @ W1b + b1b -> {new_s pk-atomic, new_p store, new_o pk-atomic}.
__global__ __launch_bounds__(512, 2) void gemm2_k(
    const ushort_t* __restrict__ hbuf, const int* __restrict__ edges,
    const ushort_t* __restrict__ W1b_p, const float* __restrict__ b1b,
    ushort_t* __restrict__ pooled_bf, float* __restrict__ new_p)
{
    __shared__ __align__(16) ushort_t Wl[49152]; // 96 KB
    const int tid = threadIdx.x;
    const int l = tid & 63;
    const int w = tid >> 6;
    const int q = l >> 5;
    const int r32 = l & 31;

    {
        const short8* s = reinterpret_cast<const short8*>(W1b_p);
        short8* d = reinterpret_cast<short8*>(Wl);
        #pragma unroll
        for (int i = 0; i < 12; ++i) d[i * 512 + tid] = s[i * 512 + tid];
    }
    __syncthreads();

    float bias[12];
    #pragma unroll
    for (int nt = 0; nt < 12; ++nt) bias[nt] = b1b[(nt << 5) + r32];

    for (int c = blockIdx.x; c < NCH1; c += gridDim.x) {
        int trow = c * 256 + w * 32 + r32;
        int tr = trow < T_N ? trow : T_N - 1;

        short8 af[8];
        #pragma unroll
        for (int ks = 0; ks < 8; ++ks)
            af[ks] = *reinterpret_cast<const short8*>(&hbuf[(size_t)tr * 128 + (ks << 4) + (q << 3)]);

        #pragma unroll
        for (int g = 0; g < 3; ++g) {
            f32x16 acc[4] = {};
            #pragma unroll
            for (int ks = 0; ks < 8; ++ks) {
                #pragma unroll
                for (int nt2 = 0; nt2 < 4; ++nt2) {
                    short8 bf = *reinterpret_cast<const short8*>(&Wl[((ks * 12 + (g << 2) + nt2) * 64 + l) * 8]);
                    acc[nt2] = __builtin_amdgcn_mfma_f32_32x32x16_bf16(af[ks], bf, acc[nt2], 0, 0, 0);
                }
            }
            if (g == 1) {
                #pragma unroll
                for (int nt2 = 0; nt2 < 4; ++nt2) {
                    #pragma unroll
                    for (int r = 0; r < 16; ++r) {
                        int rl = (r & 3) + ((r >> 2) << 3) + (q << 2);
                        int trow2 = c * 256 + w * 32 + rl;
                        if (trow2 < T_N)
                            new_p[(size_t)trow2 * 128 + (nt2 << 5) + r32] = acc[nt2][r] + bias[4 + nt2];
                    }
                }
            } else {
                #pragma unroll
                for (int r = 0; r < 16; ++r) {
                    int rl = (r & 3) + ((r >> 2) << 3) + (q << 2);
                    int trow2 = c * 256 + w * 32 + rl;
                    bool v2 = trow2 < T_N;
                    int t2 = v2 ? trow2 : T_N - 1;
                    int2 e2 = ((const int2*)edges)[t2];
                    int seg = (g == 0) ? e2.x : e2.y;
                    ushort_t* pb = pooled_bf + (size_t)seg * 128;
                    #pragma unroll
                    for (int nt2 = 0; nt2 < 4; ++nt2) {
                        float val = acc[nt2][r] + bias[(g << 2) + nt2];
                        float other = __shfl_xor(val, 1, 64);
                        if (v2 && !(r32 & 1)) {
                            unsigned dat = (unsigned)f2bf(val) | ((unsigned)f2bf(other) << 16);
                            uint64_t addr = (uint64_t)(uintptr_t)(pb + (nt2 << 5) + r32);
                            asm volatile("global_atomic_pk_add_bf16 %0, %1, off"
                                         :: "v"(addr), "v"(dat) : "memory");
                        }
                    }
                }
            }
        }
    }
}

// K3: pooled_bf/counts -> relu(x@W2a+b2a)@W2b+b2b -> new_obj (f32, d_out).
__global__ __launch_bounds__(512, 2) void objects_k32(
    const ushort_t* __restrict__ pooled_bf, const float* __restrict__ counts,
    const ushort_t* __restrict__ W2a_p, const float* __restrict__ b2a,
    const ushort_t* __restrict__ W2b_p, const float* __restrict__ b2b,
    float* __restrict__ outp)
{
    __shared__ __align__(16) ushort_t Wa[16384];
    __shared__ __align__(16) ushort_t Wb[16384];
    __shared__ __align__(16) ushort_t hx[8][4096];
    const int tid = threadIdx.x;
    const int l = tid & 63;
    const int w = tid >> 6;
    const int q = l >> 5;
    const int r32 = l & 31;

    {
        const short8* sa = reinterpret_cast<const short8*>(W2a_p);
        const short8* sb = reinterpret_cast<const short8*>(W2b_p);
        short8* da = reinterpret_cast<short8*>(Wa);
        short8* db = reinterpret_cast<short8*>(Wb);
        #pragma unroll
        for (int i = 0; i < 4; ++i) { da[i * 512 + tid] = sa[i * 512 + tid]; db[i * 512 + tid] = sb[i * 512 + tid]; }
    }
    __syncthreads();

    float ba[4], bb[4];
    #pragma unroll
    for (int nt = 0; nt < 4; ++nt) { ba[nt] = b2a[(nt << 5) + r32]; bb[nt] = b2b[(nt << 5) + r32]; }

    for (int c = blockIdx.x; c < NCH3; c += gridDim.x) {
        int row = c * 256 + w * 32 + r32;
        int rr = row < O_N ? row : O_N - 1;
        float inv = 1.0f / fmaxf(counts[rr], 1.0f);

        short8 af[8];
        #pragma unroll
        for (int ks = 0; ks < 8; ++ks) {
            short8 raw = *reinterpret_cast<const short8*>(&pooled_bf[(size_t)rr * 128 + (ks << 4) + (q << 3)]);
            short8 a;
            #pragma unroll
            for (int j = 0; j < 8; ++j) {
                union { float f; unsigned u; } t;
                t.u = ((unsigned)(unsigned short)raw[j]) << 16;
                a[j] = (short)f2bf(t.f * inv);
            }
            af[ks] = a;
        }

        f32x16 acc[4] = {};
        #pragma unroll
        for (int ks = 0; ks < 8; ++ks) {
            #pragma unroll
            for (int nt = 0; nt < 4; ++nt) {
                short8 bf = *reinterpret_cast<const short8*>(&Wa[(((ks << 2) + nt) * 64 + l) * 8]);
                acc[nt] = __builtin_amdgcn_mfma_f32_32x32x16_bf16(af[ks], bf, acc[nt], 0, 0, 0);
            }
        }

        char* hxw = (char*)&hx[w][0];
        #pragma unroll
        for (int nt = 0; nt < 4; ++nt) {
            #pragma unroll
            for (int r = 0; r < 16; ++r) {
                int rl = (r & 3) + ((r >> 2) << 3) + (q << 2);
                float hv = fmaxf(acc[nt][r] + ba[nt], 0.0f);
                int off = rl * 256 + (((nt << 5) + r32) << 1);
                off ^= (rl & 15) << 4;
                *(ushort_t*)(hxw + off) = f2bf(hv);
            }
        }
        __syncthreads();

        short8 af2[8];
        #pragma unroll
        for (int ks = 0; ks < 8; ++ks) {
            int off = r32 * 256 + (ks << 5) + (q << 4);
            off ^= (r32 & 15) << 4;
            af2[ks] = *reinterpret_cast<const short8*>(hxw + off);
        }

        f32x16 acc2[4] = {};
        #pragma unroll
        for (int ks = 0; ks < 8; ++ks) {
            #pragma unroll
            for (int nt = 0; nt < 4; ++nt) {
                short8 bf = *reinterpret_cast<const short8*>(&Wb[(((ks << 2) + nt) * 64 + l) * 8]);
                acc2[nt] = __builtin_amdgcn_mfma_f32_32x32x16_bf16(af2[ks], bf, acc2[nt], 0, 0, 0);
            }
        }

        #pragma unroll
        for (int nt = 0; nt < 4; ++nt) {
            #pragma unroll
            for (int r = 0; r < 16; ++r) {
                int rl = (r & 3) + ((r >> 2) << 3) + (q << 2);
                int row2 = c * 256 + w * 32 + rl;
                if (row2 < O_N) outp[(size_t)row2 * 128 + (nt << 5) + r32] = acc2[nt][r] + bb[nt];
            }
        }
        __syncthreads();
    }
}

// ---------------- fallback path (round-1, known-good) ----------------
__device__ __forceinline__ void stage_w(const unsigned short* __restrict__ src,
                                        unsigned short* __restrict__ dst, int tid) {
    const short8* s = reinterpret_cast<const short8*>(src);
    short8* d = reinterpret_cast<short8*>(dst);
    d[tid] = s[tid];
    d[tid + 256] = s[tid + 256];
}

__global__ __launch_bounds__(256, 2) void triples_kernel(
    const float* __restrict__ obj_vecs, const float* __restrict__ pred_vecs,
    const int* __restrict__ edges,
    const unsigned short* __restrict__ W1a_p, const float* __restrict__ b1a,
    const unsigned short* __restrict__ W1b_p, const float* __restrict__ b1b,
    float* __restrict__ pooled, float* __restrict__ new_p, float* __restrict__ counts)
{
    __shared__ __align__(16) unsigned short Apack[24576];
    __shared__ __align__(16) unsigned short Wbuf[2][4096];
    __shared__ int sseg[64], oseg[64];
    const int tid = threadIdx.x;
    const int lane = tid & 63;
    const int w = tid >> 6;
    const int t0 = blockIdx.x * 64;
    if (tid < 64) {
        int s = edges[2 * (t0 + tid)];
        int o = edges[2 * (t0 + tid) + 1];
        sseg[tid] = s; oseg[tid] = o;
        atomicAdd(&counts[s], 1.0f);
        atomicAdd(&counts[o], 1.0f);
    }
    __syncthreads();
    for (int it = 0; it < 24; ++it) {
        int idx = it * 256 + tid;
        int r = idx / 96;
        int c = (idx % 96) * 4;
        const float* srcp;
        if (c < 128)      srcp = obj_vecs  + (size_t)sseg[r] * 128 + c;
        else if (c < 256) srcp = pred_vecs + (size_t)(t0 + r) * 128 + (c - 128);
        else              srcp = obj_vecs  + (size_t)oseg[r] * 128 + (c - 256);
        f32x4 v = *reinterpret_cast<const f32x4*>(srcp);
        int off = (((r >> 4) * 12 + (c >> 5)) << 9)
                + (((r & 15) | (((c & 31) >> 3) << 4)) << 3) + (c & 7);
        Apack[off + 0] = f2bf(v[0]); Apack[off + 1] = f2bf(v[1]);
        Apack[off + 2] = f2bf(v[2]); Apack[off + 3] = f2bf(v[3]);
    }
    stage_w(W1a_p, Wbuf[0], tid);
    __syncthreads();
    f32x4 acc[8];
    #pragma unroll
    for (int n = 0; n < 8; ++n) acc[n] = (f32x4){0.f, 0.f, 0.f, 0.f};
    for (int kk = 0; kk < 12; ++kk) {
        if (kk < 11) stage_w(W1a_p + (kk + 1) * 4096, Wbuf[(kk + 1) & 1], tid);
        short8 a = *reinterpret_cast<const short8*>(&Apack[((w * 12 + kk) << 9) + (lane << 3)]);
        const unsigned short* wb = Wbuf[kk & 1];
        #pragma unroll
        for (int n = 0; n < 8; ++n) {
            short8 b = *reinterpret_cast<const short8*>(&wb[((n << 6) + lane) << 3]);
            acc[n] = __builtin_amdgcn_mfma_f32_16x16x32_bf16(a, b, acc[n], 0, 0, 0);
        }
        __syncthreads();
    }
    #pragma unroll
    for (int n = 0; n < 8; ++n) {
        int col = (n << 4) + (lane & 15);
        float bias = b1a[col];
        int base = ((w * 4 + (col >> 5)) << 9) + (col & 7);
        int chi = ((col & 31) >> 3) << 4;
        #pragma unroll
        for (int jj = 0; jj < 4; ++jj) {
            int rloc = ((lane >> 4) << 2) + jj;
            float hv = acc[n][jj] + bias;
            hv = hv > 0.f ? hv : 0.f;
            Apack[base + ((rloc | chi) << 3)] = f2bf(hv);
        }
    }
    for (int g = 0; g < 3; ++g) {
        const unsigned short* Wsrc = W1b_p + g * 16384;
        stage_w(Wsrc, Wbuf[0], tid);
        __syncthreads();
        f32x4 acc2[8];
        #pragma unroll
        for (int n = 0; n < 8; ++n) acc2[n] = (f32x4){0.f, 0.f, 0.f, 0.f};
        for (int kk = 0; kk < 4; ++kk) {
            if (kk < 3) stage_w(Wsrc + (kk + 1) * 4096, Wbuf[(kk + 1) & 1], tid);
            short8 a = *reinterpret_cast<const short8*>(&Apack[((w * 4 + kk) << 9) + (lane << 3)]);
            const unsigned short* wb = Wbuf[kk & 1];
            #pragma unroll
            for (int n = 0; n < 8; ++n) {
                short8 b = *reinterpret_cast<const short8*>(&wb[((n << 6) + lane) << 3]);
                acc2[n] = __builtin_amdgcn_mfma_f32_16x16x32_bf16(a, b, acc2[n], 0, 0, 0);
            }
            __syncthreads();
        }
        #pragma unroll
        for (int n = 0; n < 8; ++n) {
            int col = (n << 4) + (lane & 15);
            float bias = b1b[g * 128 + col];
            #pragma unroll
            for (int jj = 0; jj < 4; ++jj) {
                int rloc = (w << 4) + ((lane >> 4) << 2) + jj;
                float val = acc2[n][jj] + bias;
                if (g == 1) {
                    new_p[(size_t)(t0 + rloc) * 128 + col] = val;
                } else {
                    int seg = (g == 0) ? sseg[rloc] : oseg[rloc];
                    atomicAdd(&pooled[(size_t)seg * 128 + col], val);
                }
            }
        }
    }
}

__global__ __launch_bounds__(256, 2) void objects_kernel(
    const float* __restrict__ counts,
    const unsigned short* __restrict__ W2a_p, const float* __restrict__ b2a,
    const unsigned short* __restrict__ W2b_p, const float* __restrict__ b2b,
    float* __restrict__ inout)
{
    __shared__ __align__(16) unsigned short Apack[8192];
    __shared__ __align__(16) unsigned short Hpack[8192];
    __shared__ __align__(16) unsigned short Wbuf[2][4096];
    const int tid = threadIdx.x;
    const int lane = tid & 63;
    const int w = tid >> 6;
    const int r0 = blockIdx.x * 64;
    for (int it = 0; it < 8; ++it) {
        int idx = it * 256 + tid;
        int r = idx >> 5;
        int c = (idx & 31) << 2;
        int row = r0 + r;
        float vals[4] = {0.f, 0.f, 0.f, 0.f};
        if (row < O_N) {
            f32x4 v = *reinterpret_cast<const f32x4*>(&inout[(size_t)row * 128 + c]);
            float inv = 1.0f / fmaxf(counts[row], 1.0f);
            vals[0] = v[0] * inv; vals[1] = v[1] * inv;
            vals[2] = v[2] * inv; vals[3] = v[3] * inv;
        }
        int off = (((r >> 4) * 4 + (c >> 5)) << 9)
                + (((r & 15) | (((c & 31) >> 3) << 4)) << 3) + (c & 7);
        Apack[off + 0] = f2bf(vals[0]); Apack[off + 1] = f2bf(vals[1]);
        Apack[off + 2] = f2bf(vals[2]); Apack[off + 3] = f2bf(vals[3]);
    }
    stage_w(W2a_p, Wbuf[0], tid);
    __syncthreads();
    f32x4 acc[8];
    #pragma unroll
    for (int n = 0; n < 8; ++n) acc[n] = (f32x4){0.f, 0.f, 0.f, 0.f};
    for (int kk = 0; kk < 4; ++kk) {
        if (kk < 3) stage_w(W2a_p + (kk + 1) * 4096, Wbuf[(kk + 1) & 1], tid);
        short8 a = *reinterpret_cast<const short8*>(&Apack[((w * 4 + kk) << 9) + (lane << 3)]);
        const unsigned short* wb = Wbuf[kk & 1];
        #pragma unroll
        for (int n = 0; n < 8; ++n) {
            short8 b = *reinterpret_cast<const short8*>(&wb[((n << 6) + lane) << 3]);
            acc[n] = __builtin_amdgcn_mfma_f32_16x16x32_bf16(a, b, acc[n], 0, 0, 0);
        }
        __syncthreads();
    }
    #pragma unroll
    for (int n = 0; n < 8; ++n) {
        int col = (n << 4) + (lane & 15);
        float bias = b2a[col];
        int base = ((w * 4 + (col >> 5)) << 9) + (col & 7);
        int chi = ((col & 31) >> 3) << 4;
        #pragma unroll
        for (int jj = 0; jj < 4; ++jj) {
            int rloc = ((lane >> 4) << 2) + jj;
            float hv = acc[n][jj] + bias;
            hv = hv > 0.f ? hv : 0.f;
            Hpack[base + ((rloc | chi) << 3)] = f2bf(hv);
        }
    }
    stage_w(W2b_p, Wbuf[0], tid);
    __syncthreads();
    f32x4 acc2[8];
    #pragma unroll
    for (int n = 0; n < 8; ++n) acc2[n] = (f32x4){0.f, 0.f, 0.f, 0.f};
    for (int kk = 0; kk < 4; ++kk) {
        if (kk < 3) stage_w(W2b_p + (kk + 1) * 4096, Wbuf[(kk + 1) & 1], tid);
        short8 a = *reinterpret_cast<const short8*>(&Hpack[((w * 4 + kk) << 9) + (lane << 3)]);
        const unsigned short* wb = Wbuf[kk & 1];
        #pragma unroll
        for (int n = 0; n < 8; ++n) {
            short8 b = *reinterpret_cast<const short8*>(&wb[((n << 6) + lane) << 3]);
            acc2[n] = __builtin_amdgcn_mfma_f32_16x16x32_bf16(a, b, acc2[n], 0, 0, 0);
        }
        __syncthreads();
    }
    #pragma unroll
    for (int n = 0; n < 8; ++n) {
        int col = (n << 4) + (lane & 15);
        float bias = b2b[col];
        #pragma unroll
        for (int jj = 0; jj < 4; ++jj) {
            int rloc = (w << 4) + ((lane >> 4) << 2) + jj;
            int row = r0 + rloc;
            if (row < O_N) inout[(size_t)row * 128 + col] = acc2[n][jj] + bias;
        }
    }
}

extern "C" void kernel_launch(void* const* d_in, const int* in_sizes, int n_in,
                              void* d_out, int out_size, void* d_ws, size_t ws_size,
                              hipStream_t stream)
{
    const float* obj   = (const float*)d_in[0];
    const float* pred  = (const float*)d_in[1];
    const int*   edges = (const int*)d_in[2];
    const float* W1a = (const float*)d_in[3];
    const float* b1a = (const float*)d_in[4];
    const float* W1b = (const float*)d_in[5];
    const float* b1b = (const float*)d_in[6];
    const float* W2a = (const float*)d_in[7];
    const float* b2a = (const float*)d_in[8];
    const float* W2b = (const float*)d_in[9];
    const float* b2b = (const float*)d_in[10];

    float* out    = (float*)d_out;
    float* new_p  = out + (size_t)O_N * 128;   // T x 128

    uintptr_t wsbase = (uintptr_t)d_ws;
    float* counts = (float*)wsbase;
    uintptr_t p = (wsbase + (size_t)O_N * 4 + 255) & ~(uintptr_t)255;
    ushort_t* pooled_bf = (ushort_t*)p;  p += (size_t)O_N * 128 * 2;   // 25.6 MB
    ushort_t* W1a_p = (ushort_t*)p;  p += (size_t)49152 * 2;           // 16x16 frag pack
    ushort_t* W1b_p = (ushort_t*)p;  p += (size_t)49152 * 2;           // 32x32 frag pack
    ushort_t* W2a_p = (ushort_t*)p;  p += (size_t)16384 * 2;
    ushort_t* W2b_p = (ushort_t*)p;  p += (size_t)16384 * 2;
    ushort_t* hbuf  = (ushort_t*)p;  p += (size_t)T_N * 128 * 2;       // 102.4 MB row-major
    size_t need = p - wsbase;

    hipMemsetAsync(counts, 0, (size_t)O_N * sizeof(float), stream);

    if (ws_size >= need) {
        hipMemsetAsync(pooled_bf, 0, (size_t)O_N * 128 * 2, stream);

        pack_b<<<192, 256, 0, stream>>>(W1a, W1a_p, 384, 8, 128, 0);    // 16x16 for gemm1
        pack_b32<<<192, 256, 0, stream>>>(W1b, W1b_p, 8, 12, 384, 0);
        pack_b32<<<64, 256, 0, stream>>>(W2a, W2a_p, 8, 4, 128, 0);
        pack_b32<<<64, 256, 0, stream>>>(W2b, W2b_p, 8, 4, 128, 0);
        counts_k<<<(T_N + 255) / 256, 256, 0, stream>>>(edges, counts);

        gemm1_k<<<256, 1024, 0, stream>>>(obj, pred, edges, W1a_p, b1a, hbuf);
        gemm2_k<<<256, 512, 0, stream>>>(hbuf, edges, W1b_p, b1b, pooled_bf, new_p);
        objects_k32<<<391, 512, 0, stream>>>(pooled_bf, counts, W2a_p, b2a, W2b_p, b2b, out);
    } else {
        // fallback: round-1 fused path (correct, slower); pooled f32 in d_out
        float* pooled = out;
        hipMemsetAsync(pooled, 0, (size_t)O_N * 128 * sizeof(float), stream);

        pack_b<<<192, 256, 0, stream>>>(W1a, W1a_p, 384, 8, 128, 0);
        pack_b<<<64, 256, 0, stream>>>(W1b, W1b_p,         128, 8, 384, 0);
        pack_b<<<64, 256, 0, stream>>>(W1b, W1b_p + 16384, 128, 8, 384, 128);
        pack_b<<<64, 256, 0, stream>>>(W1b, W1b_p + 32768, 128, 8, 384, 256);
        pack_b<<<64, 256, 0, stream>>>(W2a, W2a_p, 128, 8, 128, 0);
        pack_b<<<64, 256, 0, stream>>>(W2b, W2b_p, 128, 8, 128, 0);

        triples_kernel<<<T_N / 64, 256, 0, stream>>>(obj, pred, edges,
                                                     W1a_p, b1a, W1b_p, b1b,
                                                     pooled, new_p, counts);
        objects_kernel<<<(O_N + 63) / 64, 256, 0, stream>>>(counts, W2a_p, b2a, W2b_p, b2b, out);
    }
}